// Round 14
// baseline (2248.325 us; speedup 1.0000x reference)
//
#include <hip/hip_runtime.h>
#include <math.h>

// Problem constants
#define BB 64      // batch
#define SS 512     // seq
#define EE 256     // embed
#define HH 512     // hidden

// Round-14: r13 LL-packet structure + v_pk_fma_f32 matvec (2x fp32 rate,
// bit-identical IEEE fma) + sleepless data polls.
// r11/r13 evidence: three different exchange protocols all ~3.9us/step ->
// rendezvous ~3.0us is protocol-insensitive; remaining reducible term is
// the ~0.9us compute-on-chain, halved here via packed math with op_sel
// broadcast of the h scalar (no extra moves).
#define NGROUPS 16
#define GSLICES 8          // slices per layer per group
#define LBLK 16            // blocks per group (2 layers x 8 slices)
#define BPG 4              // batches per group
#define RECT 512           // threads per rec block
#define RING 16            // ring slots per layer
#define BARK 8             // full barrier every BARK steps

#define SLOTF (GSLICES * 512)        // floats per (layer,slot): 2048 pkts x 2
#define GPKF  (2 * RING * SLOTF)     // floats per group packet region

// packed fma with h broadcast from lo/hi half of the h register pair
#define PK_LO(d, w, h) \
  asm("v_pk_fma_f32 %0, %1, %2, %0 op_sel:[0,0,0] op_sel_hi:[1,0,1]" \
      : "+v"(d) : "v"(w), "v"(h))
#define PK_HI(d, w, h) \
  asm("v_pk_fma_f32 %0, %1, %2, %0 op_sel:[0,1,0] op_sel_hi:[1,1,1]" \
      : "+v"(d) : "v"(w), "v"(h))

// ---------------------------------------------------------------------------

// W transpose: WT[j][i] = W[i][j], 512x512
__global__ void transpose512(const float* __restrict__ in, float* __restrict__ out) {
  __shared__ float tile[32][33];
  int bx = blockIdx.x * 32, by = blockIdx.y * 32;
  int x = threadIdx.x, y0 = threadIdx.y;  // block (32,8)
  for (int dy = 0; dy < 32; dy += 8)
    tile[y0 + dy][x] = in[(size_t)(by + y0 + dy) * HH + bx + x];
  __syncthreads();
  for (int dy = 0; dy < 32; dy += 8)
    out[(size_t)(bx + y0 + dy) * HH + by + x] = tile[x][y0 + dy];
}

// Tiled GEMM with gather: C[m][n] = sum_k emb[x[m]][k] * Wn[n][k] + b1[n]+b2[n]
template <int K, bool GATHER>
__global__ __launch_bounds__(256) void xp_gemm(
    const float* __restrict__ Asrc, const int* __restrict__ xidx,
    const float* __restrict__ emb, const float* __restrict__ Wn,
    const float* __restrict__ bias1, const float* __restrict__ bias2,
    float* __restrict__ C) {
  const int tid = threadIdx.x;
  const int m0 = blockIdx.x * 64;
  const int n0 = blockIdx.y * 64;
  __shared__ alignas(16) float As[32][68];
  __shared__ alignas(16) float Bs[32][68];
  __shared__ int xs[64];
  if (GATHER) {
    if (tid < 64) xs[tid] = xidx[m0 + tid];
    __syncthreads();
  }
  float acc[4][4] = {};
  const int ty = tid >> 4, tx = tid & 15;
  const int row = tid >> 2;          // 0..63
  const int kc = (tid & 3) * 8;      // 0,8,16,24

  for (int k0 = 0; k0 < K; k0 += 32) {
    const float* ap;
    if (GATHER) ap = emb + (size_t)xs[row] * EE + (k0 + kc);
    else        ap = Asrc + (size_t)(m0 + row) * K + (k0 + kc);
    float4 av0 = *(const float4*)ap;
    float4 av1 = *(const float4*)(ap + 4);
    const float* bp = Wn + (size_t)(n0 + row) * K + (k0 + kc);
    float4 bv0 = *(const float4*)bp;
    float4 bv1 = *(const float4*)(bp + 4);
    __syncthreads();
    As[kc + 0][row] = av0.x; As[kc + 1][row] = av0.y;
    As[kc + 2][row] = av0.z; As[kc + 3][row] = av0.w;
    As[kc + 4][row] = av1.x; As[kc + 5][row] = av1.y;
    As[kc + 6][row] = av1.z; As[kc + 7][row] = av1.w;
    Bs[kc + 0][row] = bv0.x; Bs[kc + 1][row] = bv0.y;
    Bs[kc + 2][row] = bv0.z; Bs[kc + 3][row] = bv0.w;
    Bs[kc + 4][row] = bv1.x; Bs[kc + 5][row] = bv1.y;
    Bs[kc + 6][row] = bv1.z; Bs[kc + 7][row] = bv1.w;
    __syncthreads();
#pragma unroll 8
    for (int k = 0; k < 32; ++k) {
      float4 av = *(const float4*)&As[k][ty * 4];
      float4 bv = *(const float4*)&Bs[k][tx * 4];
      acc[0][0] += av.x * bv.x; acc[0][1] += av.x * bv.y;
      acc[0][2] += av.x * bv.z; acc[0][3] += av.x * bv.w;
      acc[1][0] += av.y * bv.x; acc[1][1] += av.y * bv.y;
      acc[1][2] += av.y * bv.z; acc[1][3] += av.y * bv.w;
      acc[2][0] += av.z * bv.x; acc[2][1] += av.z * bv.y;
      acc[2][2] += av.z * bv.z; acc[2][3] += av.z * bv.w;
      acc[3][0] += av.w * bv.x; acc[3][1] += av.w * bv.y;
      acc[3][2] += av.w * bv.z; acc[3][3] += av.w * bv.w;
    }
  }
  float bj[4];
#pragma unroll
  for (int j = 0; j < 4; ++j) {
    int n = n0 + tx * 4 + j;
    bj[j] = bias1[n] + bias2[n];
  }
#pragma unroll
  for (int i = 0; i < 4; ++i) {
    float4 cv = make_float4(acc[i][0] + bj[0], acc[i][1] + bj[1],
                            acc[i][2] + bj[2], acc[i][3] + bj[3]);
    *(float4*)&C[(size_t)(m0 + ty * 4 + i) * HH + n0 + tx * 4] = cv;
  }
}

// Zero packet region + barrier flags AT THE IC. Runs every launch.
__global__ void init_sync(float* __restrict__ pkts, unsigned* __restrict__ flags) {
  size_t i = (size_t)blockIdx.x * 256 + threadIdx.x;
  if (i < (size_t)NGROUPS * GPKF)
    __hip_atomic_store(&pkts[i], 0.f, __ATOMIC_RELAXED, __HIP_MEMORY_SCOPE_SYSTEM);
  if (i < NGROUPS * LBLK * 32)
    __hip_atomic_store(&flags[i], 0u, __ATOMIC_RELAXED, __HIP_MEMORY_SCOPE_SYSTEM);
}

// Poll 4 packets (32B) at pb + tid*32 (tight loop, self-paced by round trip).
__device__ __forceinline__ void poll2(const float* pb, unsigned tg,
                                      float4& u0, float4& u1) {
  for (;;) {
    asm volatile(
      "global_load_dwordx4 %0, %2, off sc0 sc1\n\t"
      "global_load_dwordx4 %1, %2, off offset:16 sc0 sc1\n\t"
      "s_waitcnt vmcnt(0)"
      : "=&v"(u0), "=&v"(u1) : "v"(pb) : "memory");
    if (__float_as_uint(u0.y) == tg && __float_as_uint(u0.w) == tg &&
        __float_as_uint(u1.y) == tg && __float_as_uint(u1.w) == tg) break;
  }
}

// Poll 8 packets from two regions (h0 + h1) in one retry loop.
__device__ __forceinline__ void poll4(const float* pa, unsigned tga,
                                      const float* pb, unsigned tgb,
                                      float4& a0, float4& a1,
                                      float4& b0, float4& b1) {
  for (;;) {
    asm volatile(
      "global_load_dwordx4 %0, %4, off sc0 sc1\n\t"
      "global_load_dwordx4 %1, %4, off offset:16 sc0 sc1\n\t"
      "global_load_dwordx4 %2, %5, off sc0 sc1\n\t"
      "global_load_dwordx4 %3, %5, off offset:16 sc0 sc1\n\t"
      "s_waitcnt vmcnt(0)"
      : "=&v"(a0), "=&v"(a1), "=&v"(b0), "=&v"(b1)
      : "v"(pa), "v"(pb) : "memory");
    if (__float_as_uint(a0.y) == tga && __float_as_uint(a0.w) == tga &&
        __float_as_uint(a1.y) == tga && __float_as_uint(a1.w) == tga &&
        __float_as_uint(b0.y) == tgb && __float_as_uint(b0.w) == tgb &&
        __float_as_uint(b1.y) == tgb && __float_as_uint(b1.w) == tgb) break;
  }
}

// Scatter 4 packet payloads into the staged LDS h array.
__device__ __forceinline__ void scat(float* hs, int q0, float4 u0, float4 u1) {
  int b = (q0 >> 6) & 3;
  int j0 = (q0 >> 8) * 64 + (q0 & 63);
  *(float4*)&hs[b * HH + j0] = make_float4(u0.x, u0.z, u1.x, u1.z);
}

// Packed matvec from LDS-staged h: acc2[b] += sum_j w[j] * h[b][jg*16+j].
// w is float2[32] (pairs of outputs); h scalar broadcast via op_sel.
__device__ __forceinline__ void fma_mv_pk(float2 acc2[4][2], const float2 w[32],
                                          const float* h, int jg) {
#pragma unroll
  for (int q = 0; q < 4; ++q) {
#pragma unroll
    for (int b = 0; b < 4; ++b) {
      float4 hv = *(const float4*)&h[b * HH + jg * 16 + q * 4];
      float2 h01 = {hv.x, hv.y};
      float2 h23 = {hv.z, hv.w};
      PK_LO(acc2[b][0], w[(q * 4 + 0) * 2 + 0], h01);
      PK_LO(acc2[b][1], w[(q * 4 + 0) * 2 + 1], h01);
      PK_HI(acc2[b][0], w[(q * 4 + 1) * 2 + 0], h01);
      PK_HI(acc2[b][1], w[(q * 4 + 1) * 2 + 1], h01);
      PK_LO(acc2[b][0], w[(q * 4 + 2) * 2 + 0], h23);
      PK_LO(acc2[b][1], w[(q * 4 + 2) * 2 + 1], h23);
      PK_HI(acc2[b][0], w[(q * 4 + 3) * 2 + 0], h23);
      PK_HI(acc2[b][1], w[(q * 4 + 3) * 2 + 1], h23);
    }
  }
}

// Fused 2-layer recurrence (r13 structure). bid: grp = bid&15, role = bid>>4.
// Packets: h0_s -> layer 0, slot s&15, tag s+1. h1_t -> layer 1, slot t&15,
// tag t+1 (written at step s=t+1). Consumers at step s read h0_{s-1} (tag s)
// and, for L1, h1_{s-2} (tag s-1).
__global__ __launch_bounds__(RECT, 2) void rec_fused(
    const float* __restrict__ xp,      // [BB][SS][HH]
    const float* __restrict__ WThh0,   // [HH][HH]
    const float* __restrict__ WTih1,   // [HH][HH]
    const float* __restrict__ WThh1,   // [HH][HH]
    const float* __restrict__ b_ih1,
    const float* __restrict__ b_hh1,
    float* __restrict__ pooled,        // [BB][HH]
    float* __restrict__ pkts,          // [NGROUPS][2][RING][GSLICES*256 pkts]
    unsigned* __restrict__ flags) {    // [NGROUPS][LBLK][32]
  const int tid = threadIdx.x;
  const int bid = blockIdx.x;
  const int grp = bid & 15;
  const int role = bid >> 4;          // 0..15
  const bool isL1 = role >= GSLICES;
  const int slice = role & 7;
  const int oo4 = tid & 15;
  const int jg = tid >> 4;            // 0..31
  const int obase = slice * 64 + oo4 * 4;

  // ---- weights into float2 registers (once); pin against remat ----
  float2 wregA[32], wregB[32];
  {
    const float* wb = isL1 ? WThh1 : WThh0;
#pragma unroll
    for (int j = 0; j < 16; ++j) {
      float4 t = *(const float4*)&wb[(size_t)(jg * 16 + j) * HH + obase];
      wregB[2 * j + 0] = make_float2(t.x, t.y);
      wregB[2 * j + 1] = make_float2(t.z, t.w);
    }
#pragma unroll
    for (int j = 0; j < 32; ++j)
      asm volatile("" : "+v"(wregB[j]));
  }
  if (isL1) {
#pragma unroll
    for (int j = 0; j < 16; ++j) {
      float4 t = *(const float4*)&WTih1[(size_t)(jg * 16 + j) * HH + obase];
      wregA[2 * j + 0] = make_float2(t.x, t.y);
      wregA[2 * j + 1] = make_float2(t.z, t.w);
    }
#pragma unroll
    for (int j = 0; j < 32; ++j)
      asm volatile("" : "+v"(wregA[j]));
  }

  float* pk = pkts + (size_t)grp * GPKF;
  unsigned* flg = flags + grp * (LBLK * 32);

  __shared__ alignas(16) float hA[BPG * HH];   // 8 KB
  __shared__ alignas(16) float hB[BPG * HH];   // 8 KB
  __shared__ float part[8][16][17];

  const int wave = tid >> 6, wl = tid & 63;
  const int fo = tid & 63;
  const int fbb = (tid >> 6) & 3;
  const int fog = slice * 64 + fo;
  const size_t fxbase = (size_t)(grp * BPG + fbb) * (SS * HH) + fog;
  float pacc = 0.f;
  float bs = 0.f;
  if (tid < 256) bs = b_ih1[fog] + b_hh1[fog];

  const int q0 = tid * 4;            // this thread's 4 packets
  const int toff = tid * 8;          // float offset of those packets
  const int wpo = slice * 512 + (fbb * 64 + fo) * 2;   // writer pkt offset

  for (int s = 0; s < SS; ++s) {
    float xv = 0.f;
    // ---- stage: poll packets (detect == stage) ----
    if (!isL1) {
      if (tid < 256) xv = xp[fxbase + (size_t)s * HH];
      if (s >= 1) {
        float4 u0, u1;
        const float* pb = pk + (size_t)((s - 1) & 15) * SLOTF + toff;
        poll2(pb, (unsigned)s, u0, u1);
        scat(hA, q0, u0, u1);
      }
    } else {
      if (s >= 2) {
        float4 a0, a1, b0, b1;
        const float* pa = pk + (size_t)((s - 1) & 15) * SLOTF + toff;
        const float* pb = pk + (size_t)(RING + ((s - 2) & 15)) * SLOTF + toff;
        poll4(pa, (unsigned)s, pb, (unsigned)(s - 1), a0, a1, b0, b1);
        scat(hA, q0, a0, a1);
        scat(hB, q0, b0, b1);
      } else if (s == 1) {
        float4 a0, a1;
        const float* pa = pk + (size_t)0 * SLOTF + toff;
        poll2(pa, 1u, a0, a1);
        scat(hA, q0, a0, a1);
      }
    }
    __syncthreads();   // stage visible

    // ---- packed matvec + reduce ----
    float2 acc2[4][2] = {{{0,0},{0,0}},{{0,0},{0,0}},{{0,0},{0,0}},{{0,0},{0,0}}};
    if (s >= 1) {
      if (!isL1) {
        fma_mv_pk(acc2, wregB, hA, jg);
      } else {
        fma_mv_pk(acc2, wregA, hA, jg);             // W_ih1 * h0_{s-1}
        if (s >= 2) fma_mv_pk(acc2, wregB, hB, jg); // + W_hh1 * h1_{s-2}
      }
#pragma unroll
      for (int b = 0; b < BPG; ++b) {
        float4 a = make_float4(acc2[b][0].x, acc2[b][0].y,
                               acc2[b][1].x, acc2[b][1].y);
        a.x += __shfl_down(a.x, 32); a.y += __shfl_down(a.y, 32);
        a.z += __shfl_down(a.z, 32); a.w += __shfl_down(a.w, 32);
        a.x += __shfl_down(a.x, 16); a.y += __shfl_down(a.y, 16);
        a.z += __shfl_down(a.z, 16); a.w += __shfl_down(a.w, 16);
        if (wl < 16) {
          part[wave][wl][b * 4 + 0] = a.x;
          part[wave][wl][b * 4 + 1] = a.y;
          part[wave][wl][b * 4 + 2] = a.z;
          part[wave][wl][b * 4 + 3] = a.w;
        }
      }
    }
    __syncthreads();   // part visible

    // ---- finalize (waves 0-3): reduce + tanh + LL-packet publish ----
    if (tid < 256) {
      if (!isL1) {
        float v = xv;
        if (s >= 1) {
#pragma unroll
          for (int w = 0; w < 8; ++w) v += part[w][fo >> 2][fbb * 4 + (fo & 3)];
        }
        float h = tanhf(v);
        float* pw = pk + (size_t)(s & 15) * SLOTF + wpo;
        float2 pkt; pkt.x = h; pkt.y = __uint_as_float((unsigned)(s + 1));
        asm volatile("global_store_dwordx2 %0, %1, off sc0 sc1"
                     :: "v"(pw), "v"(pkt) : "memory");
      } else if (s >= 1) {
        float v = bs;
#pragma unroll
        for (int w = 0; w < 8; ++w) v += part[w][fo >> 2][fbb * 4 + (fo & 3)];
        float h = tanhf(v);
        pacc += h;
        float* pw = pk + (size_t)(RING + ((s - 1) & 15)) * SLOTF + wpo;
        float2 pkt; pkt.x = h; pkt.y = __uint_as_float((unsigned)s);
        asm volatile("global_store_dwordx2 %0, %1, off sc0 sc1"
                     :: "v"(pw), "v"(pkt) : "memory");
      }
      // no vmcnt wait: the packet store IS the release
    }

    // ---- periodic full barrier (skew bound: drift < BARK < RING) ----
    if ((s & (BARK - 1)) == (BARK - 1)) {
      unsigned bt = (unsigned)((s >> 3) + 1);
      if (tid == 0) {
        unsigned* fp = flg + role * 32;
        asm volatile("global_store_dword %0, %1, off sc0 sc1"
                     :: "v"(fp), "v"(bt) : "memory");
      }
      if (tid < LBLK) {
        const unsigned* fp = flg + tid * 32;
        unsigned v;
        do {
          asm volatile("global_load_dword %0, %1, off sc0 sc1\n\ts_waitcnt vmcnt(0)"
                       : "=v"(v) : "v"(fp) : "memory");
          if (v < bt) __builtin_amdgcn_s_sleep(2);
        } while (v < bt);
      }
      __syncthreads();
    }
  }

  // ---- L1 epilogue: h1_511 from h0_511 (tag 512) and h1_510 (tag 511) ----
  if (isL1) {
    float4 a0, a1, b0, b1;
    const float* pa = pk + (size_t)15 * SLOTF + toff;
    const float* pb = pk + (size_t)(RING + 14) * SLOTF + toff;
    poll4(pa, (unsigned)SS, pb, (unsigned)(SS - 1), a0, a1, b0, b1);
    scat(hA, q0, a0, a1);
    scat(hB, q0, b0, b1);
    __syncthreads();
    float2 acc2[4][2] = {{{0,0},{0,0}},{{0,0},{0,0}},{{0,0},{0,0}},{{0,0},{0,0}}};
    fma_mv_pk(acc2, wregA, hA, jg);
    fma_mv_pk(acc2, wregB, hB, jg);
#pragma unroll
    for (int b = 0; b < BPG; ++b) {
      float4 a = make_float4(acc2[b][0].x, acc2[b][0].y,
                             acc2[b][1].x, acc2[b][1].y);
      a.x += __shfl_down(a.x, 32); a.y += __shfl_down(a.y, 32);
      a.z += __shfl_down(a.z, 32); a.w += __shfl_down(a.w, 32);
      a.x += __shfl_down(a.x, 16); a.y += __shfl_down(a.y, 16);
      a.z += __shfl_down(a.z, 16); a.w += __shfl_down(a.w, 16);
      if (wl < 16) {
        part[wave][wl][b * 4 + 0] = a.x;
        part[wave][wl][b * 4 + 1] = a.y;
        part[wave][wl][b * 4 + 2] = a.z;
        part[wave][wl][b * 4 + 3] = a.w;
      }
    }
    __syncthreads();
    if (tid < 256) {
      float v = bs;
#pragma unroll
      for (int w = 0; w < 8; ++w) v += part[w][fo >> 2][fbb * 4 + (fo & 3)];
      pacc += tanhf(v);
      pooled[(size_t)(grp * BPG + fbb) * HH + fog] = pacc * (1.0f / SS);
    }
  }
}

// Final head: out[b][c] = sum_k pooled[b][k] * W_out[c][k] + b_out[c]
__global__ void out_kernel(const float* __restrict__ pooled,
                           const float* __restrict__ W_out,
                           const float* __restrict__ b_out,
                           float* __restrict__ out) {
  int tid = threadIdx.x;
  if (tid >= BB * 2) return;
  int b = tid >> 1, c = tid & 1;
  float acc = b_out[c];
  for (int k = 0; k < HH; ++k)
    acc += pooled[(size_t)b * HH + k] * W_out[(size_t)c * HH + k];
  out[(size_t)b * 2 + c] = acc;
}

extern "C" void kernel_launch(void* const* d_in, const int* in_sizes, int n_in,
                              void* d_out, int out_size, void* d_ws, size_t ws_size,
                              hipStream_t stream) {
  const int*   x     = (const int*)d_in[0];
  const float* emb   = (const float*)d_in[1];
  const float* W_ih0 = (const float*)d_in[2];
  const float* W_hh0 = (const float*)d_in[3];
  const float* b_ih0 = (const float*)d_in[4];
  const float* b_hh0 = (const float*)d_in[5];
  const float* W_ih1 = (const float*)d_in[6];
  const float* W_hh1 = (const float*)d_in[7];
  const float* b_ih1 = (const float*)d_in[8];
  const float* b_hh1 = (const float*)d_in[9];
  const float* W_out = (const float*)d_in[10];
  const float* b_out = (const float*)d_in[11];

  float* ws = (float*)d_ws;
  const size_t NBSH = (size_t)BB * SS * HH;            // 16777216
  const size_t PKF  = (size_t)NGROUPS * GPKF;          // 2,097,152 floats (8MB)
  float* xp      = ws;                    // 64 MB
  float* WThh0   = ws + NBSH;             // 1 MB
  float* WTih1   = WThh0 + HH * HH;       // 1 MB
  float* WThh1   = WTih1 + HH * HH;       // 1 MB
  float* pooled  = WThh1 + HH * HH;       // 128 KB
  float* pkts    = pooled + BB * HH;      // 8 MB
  unsigned* flags = (unsigned*)(pkts + PKF);  // 32 KB

  init_sync<<<8192, 256, 0, stream>>>(pkts, flags);

  dim3 tb(32, 8), tg(16, 16);
  transpose512<<<tg, tb, 0, stream>>>(W_hh0, WThh0);
  transpose512<<<tg, tb, 0, stream>>>(W_ih1, WTih1);
  transpose512<<<tg, tb, 0, stream>>>(W_hh1, WThh1);

  dim3 gg(512, 8);
  xp_gemm<EE, true><<<gg, 256, 0, stream>>>(nullptr, x, emb, W_ih0, b_ih0, b_hh0, xp);
  rec_fused<<<NGROUPS * LBLK, RECT, 0, stream>>>(
      xp, WThh0, WTih1, WThh1, b_ih1, b_hh1, pooled, pkts, flags);
  out_kernel<<<1, 128, 0, stream>>>(pooled, W_out, b_out, (float*)d_out);
}

// Round 15
// 1832.510 us; speedup vs baseline: 1.2269x; 1.2269x over previous
//
#include <hip/hip_runtime.h>
#include <math.h>

// Problem constants
#define BB 64      // batch
#define SS 512     // seq
#define EE 256     // embed
#define HH 512     // hidden

// Round-15: r13 LL-packet base + PER-WAVE DATAFLOW PIPELINING.
// Key structural fact: wave w's matvec j-range [64w,64w+64) == producer
// slice w == exactly the packets wave w polls (q0>>8 == wave). So the
// poll->scat->FMA pipeline is wave-private: no block-wide stage barrier.
// Early waves compute while the last producer is still in flight; only the
// part[]-reduce __syncthreads (1/step, was 2) remains. part[] is
// double-buffered by step parity (waves 4-7 run ahead into s+1 while
// finalize still reads step s). s_sleep(1) polls restored (r14 sleepless
// regressed: poll flood). Scalar FMA restored (r14 pk neutral-negative).
// RING 16->64 + BARK 8->32: full-group barrier amortized 4x; drift<=32<64.
#define NGROUPS 16
#define GSLICES 8          // slices per layer per group
#define LBLK 16            // blocks per group (2 layers x 8 slices)
#define BPG 4              // batches per group
#define RECT 512           // threads per rec block
#define RING 64            // ring slots per layer
#define BARK 32            // full barrier every BARK steps

#define SLOTF (GSLICES * 512)        // floats per (layer,slot): 2048 pkts x 2
#define GPKF  (2 * RING * SLOTF)     // floats per group packet region

// ---------------------------------------------------------------------------

// W transpose: WT[j][i] = W[i][j], 512x512
__global__ void transpose512(const float* __restrict__ in, float* __restrict__ out) {
  __shared__ float tile[32][33];
  int bx = blockIdx.x * 32, by = blockIdx.y * 32;
  int x = threadIdx.x, y0 = threadIdx.y;  // block (32,8)
  for (int dy = 0; dy < 32; dy += 8)
    tile[y0 + dy][x] = in[(size_t)(by + y0 + dy) * HH + bx + x];
  __syncthreads();
  for (int dy = 0; dy < 32; dy += 8)
    out[(size_t)(bx + y0 + dy) * HH + by + x] = tile[x][y0 + dy];
}

// Tiled GEMM with gather: C[m][n] = sum_k emb[x[m]][k] * Wn[n][k] + b1[n]+b2[n]
template <int K, bool GATHER>
__global__ __launch_bounds__(256) void xp_gemm(
    const float* __restrict__ Asrc, const int* __restrict__ xidx,
    const float* __restrict__ emb, const float* __restrict__ Wn,
    const float* __restrict__ bias1, const float* __restrict__ bias2,
    float* __restrict__ C) {
  const int tid = threadIdx.x;
  const int m0 = blockIdx.x * 64;
  const int n0 = blockIdx.y * 64;
  __shared__ alignas(16) float As[32][68];
  __shared__ alignas(16) float Bs[32][68];
  __shared__ int xs[64];
  if (GATHER) {
    if (tid < 64) xs[tid] = xidx[m0 + tid];
    __syncthreads();
  }
  float acc[4][4] = {};
  const int ty = tid >> 4, tx = tid & 15;
  const int row = tid >> 2;          // 0..63
  const int kc = (tid & 3) * 8;      // 0,8,16,24

  for (int k0 = 0; k0 < K; k0 += 32) {
    const float* ap;
    if (GATHER) ap = emb + (size_t)xs[row] * EE + (k0 + kc);
    else        ap = Asrc + (size_t)(m0 + row) * K + (k0 + kc);
    float4 av0 = *(const float4*)ap;
    float4 av1 = *(const float4*)(ap + 4);
    const float* bp = Wn + (size_t)(n0 + row) * K + (k0 + kc);
    float4 bv0 = *(const float4*)bp;
    float4 bv1 = *(const float4*)(bp + 4);
    __syncthreads();
    As[kc + 0][row] = av0.x; As[kc + 1][row] = av0.y;
    As[kc + 2][row] = av0.z; As[kc + 3][row] = av0.w;
    As[kc + 4][row] = av1.x; As[kc + 5][row] = av1.y;
    As[kc + 6][row] = av1.z; As[kc + 7][row] = av1.w;
    Bs[kc + 0][row] = bv0.x; Bs[kc + 1][row] = bv0.y;
    Bs[kc + 2][row] = bv0.z; Bs[kc + 3][row] = bv0.w;
    Bs[kc + 4][row] = bv1.x; Bs[kc + 5][row] = bv1.y;
    Bs[kc + 6][row] = bv1.z; Bs[kc + 7][row] = bv1.w;
    __syncthreads();
#pragma unroll 8
    for (int k = 0; k < 32; ++k) {
      float4 av = *(const float4*)&As[k][ty * 4];
      float4 bv = *(const float4*)&Bs[k][tx * 4];
      acc[0][0] += av.x * bv.x; acc[0][1] += av.x * bv.y;
      acc[0][2] += av.x * bv.z; acc[0][3] += av.x * bv.w;
      acc[1][0] += av.y * bv.x; acc[1][1] += av.y * bv.y;
      acc[1][2] += av.y * bv.z; acc[1][3] += av.y * bv.w;
      acc[2][0] += av.z * bv.x; acc[2][1] += av.z * bv.y;
      acc[2][2] += av.z * bv.z; acc[2][3] += av.z * bv.w;
      acc[3][0] += av.w * bv.x; acc[3][1] += av.w * bv.y;
      acc[3][2] += av.w * bv.z; acc[3][3] += av.w * bv.w;
    }
  }
  float bj[4];
#pragma unroll
  for (int j = 0; j < 4; ++j) {
    int n = n0 + tx * 4 + j;
    bj[j] = bias1[n] + bias2[n];
  }
#pragma unroll
  for (int i = 0; i < 4; ++i) {
    float4 cv = make_float4(acc[i][0] + bj[0], acc[i][1] + bj[1],
                            acc[i][2] + bj[2], acc[i][3] + bj[3]);
    *(float4*)&C[(size_t)(m0 + ty * 4 + i) * HH + n0 + tx * 4] = cv;
  }
}

// Zero packet region + barrier flags AT THE IC (grid-stride; 32MB now).
// Runs every launch (graph replays don't re-poison; stale tags must die).
__global__ void init_sync(float* __restrict__ pkts, unsigned* __restrict__ flags) {
  const size_t n = (size_t)NGROUPS * GPKF;
  const size_t stride = (size_t)gridDim.x * 256;
  for (size_t i = (size_t)blockIdx.x * 256 + threadIdx.x; i < n; i += stride)
    __hip_atomic_store(&pkts[i], 0.f, __ATOMIC_RELAXED, __HIP_MEMORY_SCOPE_SYSTEM);
  const size_t m = NGROUPS * LBLK * 32;
  for (size_t i = (size_t)blockIdx.x * 256 + threadIdx.x; i < m; i += stride)
    __hip_atomic_store(&flags[i], 0u, __ATOMIC_RELAXED, __HIP_MEMORY_SCOPE_SYSTEM);
}

__device__ __forceinline__ void fma4(float4& d, const float4 w, const float s) {
  d.x = __builtin_fmaf(w.x, s, d.x);
  d.y = __builtin_fmaf(w.y, s, d.y);
  d.z = __builtin_fmaf(w.z, s, d.z);
  d.w = __builtin_fmaf(w.w, s, d.w);
}

// Poll 4 packets (32B) at pb + tid*32; s_sleep backoff (r13-proven).
__device__ __forceinline__ void poll2(const float* pb, unsigned tg,
                                      float4& u0, float4& u1) {
  for (;;) {
    asm volatile(
      "global_load_dwordx4 %0, %2, off sc0 sc1\n\t"
      "global_load_dwordx4 %1, %2, off offset:16 sc0 sc1\n\t"
      "s_waitcnt vmcnt(0)"
      : "=&v"(u0), "=&v"(u1) : "v"(pb) : "memory");
    if (__float_as_uint(u0.y) == tg && __float_as_uint(u0.w) == tg &&
        __float_as_uint(u1.y) == tg && __float_as_uint(u1.w) == tg) break;
    __builtin_amdgcn_s_sleep(1);
  }
}

// Poll 8 packets from two regions (h0 + h1) in one retry loop.
__device__ __forceinline__ void poll4(const float* pa, unsigned tga,
                                      const float* pb, unsigned tgb,
                                      float4& a0, float4& a1,
                                      float4& b0, float4& b1) {
  for (;;) {
    asm volatile(
      "global_load_dwordx4 %0, %4, off sc0 sc1\n\t"
      "global_load_dwordx4 %1, %4, off offset:16 sc0 sc1\n\t"
      "global_load_dwordx4 %2, %5, off sc0 sc1\n\t"
      "global_load_dwordx4 %3, %5, off offset:16 sc0 sc1\n\t"
      "s_waitcnt vmcnt(0)"
      : "=&v"(a0), "=&v"(a1), "=&v"(b0), "=&v"(b1)
      : "v"(pa), "v"(pb) : "memory");
    if (__float_as_uint(a0.y) == tga && __float_as_uint(a0.w) == tga &&
        __float_as_uint(a1.y) == tga && __float_as_uint(a1.w) == tga &&
        __float_as_uint(b0.y) == tgb && __float_as_uint(b0.w) == tgb &&
        __float_as_uint(b1.y) == tgb && __float_as_uint(b1.w) == tgb) break;
    __builtin_amdgcn_s_sleep(1);
  }
}

// Scatter 4 packet payloads into the staged LDS h array (wave-private:
// lane l of wave w writes h[b=l>>4][j = w*64 + 4*(l&15) .. +4)).
__device__ __forceinline__ void scat(float* hs, int q0, float4 u0, float4 u1) {
  int b = (q0 >> 6) & 3;
  int j0 = (q0 >> 8) * 64 + (q0 & 63);
  *(float4*)&hs[b * HH + j0] = make_float4(u0.x, u0.z, u1.x, u1.z);
}

// matvec from LDS h; thread (oo4,jg) reads j in [jg*16,+16) -- which lies
// entirely inside its own wave's scat region [64*wave, 64*wave+64).
__device__ __forceinline__ void fma_mv_lds(float4 acc[4], const float4 wreg[16],
                                           const float* h, int jg) {
#pragma unroll
  for (int q = 0; q < 4; ++q) {
    float4 w0 = wreg[q * 4 + 0], w1 = wreg[q * 4 + 1];
    float4 w2 = wreg[q * 4 + 2], w3 = wreg[q * 4 + 3];
#pragma unroll
    for (int b = 0; b < 4; ++b) {
      float4 hv = *(const float4*)&h[b * HH + jg * 16 + q * 4];
      fma4(acc[b], w0, hv.x);
      fma4(acc[b], w1, hv.y);
      fma4(acc[b], w2, hv.z);
      fma4(acc[b], w3, hv.w);
    }
  }
}

// Fused 2-layer recurrence. bid: grp = bid&15, role = bid>>4
// (0..7 = L0 slices, 8..15 = L1 slices).
// Packets: h0_s -> layer 0, slot s&63, tag s+1. h1_t -> layer 1, slot t&63,
// tag t+1 (written at step s=t+1). Consumers at step s read h0_{s-1}
// (tag s) and, for L1, h1_{s-2} (tag s-1).
__global__ __launch_bounds__(RECT, 2) void rec_fused(
    const float* __restrict__ xp,      // [BB][SS][HH]
    const float* __restrict__ WThh0,   // [HH][HH]
    const float* __restrict__ WTih1,   // [HH][HH]
    const float* __restrict__ WThh1,   // [HH][HH]
    const float* __restrict__ b_ih1,
    const float* __restrict__ b_hh1,
    float* __restrict__ pooled,        // [BB][HH]
    float* __restrict__ pkts,          // [NGROUPS][2][RING][GSLICES*256 pkts]
    unsigned* __restrict__ flags) {    // [NGROUPS][LBLK][32]
  const int tid = threadIdx.x;
  const int bid = blockIdx.x;
  const int grp = bid & 15;
  const int role = bid >> 4;          // 0..15
  const bool isL1 = role >= GSLICES;
  const int slice = role & 7;
  const int oo4 = tid & 15;
  const int jg = tid >> 4;            // 0..31
  const int obase = slice * 64 + oo4 * 4;

  // ---- weights into registers (once); pin against remat (round-4 lesson) --
  float4 wregA[16], wregB[16];
  {
    const float* wb = isL1 ? WThh1 : WThh0;
#pragma unroll
    for (int j = 0; j < 16; ++j)
      wregB[j] = *(const float4*)&wb[(size_t)(jg * 16 + j) * HH + obase];
#pragma unroll
    for (int j = 0; j < 16; ++j)
      asm volatile("" : "+v"(wregB[j].x), "+v"(wregB[j].y),
                        "+v"(wregB[j].z), "+v"(wregB[j].w));
  }
  if (isL1) {
#pragma unroll
    for (int j = 0; j < 16; ++j)
      wregA[j] = *(const float4*)&WTih1[(size_t)(jg * 16 + j) * HH + obase];
#pragma unroll
    for (int j = 0; j < 16; ++j)
      asm volatile("" : "+v"(wregA[j].x), "+v"(wregA[j].y),
                        "+v"(wregA[j].z), "+v"(wregA[j].w));
  }

  float* pk = pkts + (size_t)grp * GPKF;
  unsigned* flg = flags + grp * (LBLK * 32);

  __shared__ alignas(16) float hA[BPG * HH];   // 8 KB (wave-private regions)
  __shared__ alignas(16) float hB[BPG * HH];   // 8 KB
  __shared__ float part[2][8][16][17];         // step-parity double buffer

  const int wave = tid >> 6, wl = tid & 63;
  const int fo = tid & 63;
  const int fbb = (tid >> 6) & 3;
  const int fog = slice * 64 + fo;
  const size_t fxbase = (size_t)(grp * BPG + fbb) * (SS * HH) + fog;
  float pacc = 0.f;
  float bs = 0.f;
  if (tid < 256) bs = b_ih1[fog] + b_hh1[fog];

  const int q0 = tid * 4;            // this thread's 4 packets (slice == wave)
  const int toff = tid * 8;          // float offset of those packets
  const int wpo = slice * 512 + (fbb * 64 + fo) * 2;   // writer pkt offset

  for (int s = 0; s < SS; ++s) {
    const int sp = s & 1;
    float xv = 0.f;
    // ---- per-wave poll + scat (wave-private; NO block barrier) ----
    if (!isL1) {
      if (tid < 256) xv = xp[fxbase + (size_t)s * HH];
      if (s >= 1) {
        float4 u0, u1;
        const float* pb = pk + (size_t)((s - 1) & (RING - 1)) * SLOTF + toff;
        poll2(pb, (unsigned)s, u0, u1);
        scat(hA, q0, u0, u1);
      }
    } else {
      if (s >= 2) {
        float4 a0, a1, b0, b1;
        const float* pa = pk + (size_t)((s - 1) & (RING - 1)) * SLOTF + toff;
        const float* pb = pk + (size_t)(RING + ((s - 2) & (RING - 1))) * SLOTF + toff;
        poll4(pa, (unsigned)s, pb, (unsigned)(s - 1), a0, a1, b0, b1);
        scat(hA, q0, a0, a1);
        scat(hB, q0, b0, b1);
      } else if (s == 1) {
        float4 a0, a1;
        const float* pa = pk + (size_t)0 * SLOTF + toff;
        poll2(pa, 1u, a0, a1);
        scat(hA, q0, a0, a1);
      }
    }
    // wave-private LDS write->read: drain own ds ops, pin order (rule #18)
    asm volatile("s_waitcnt lgkmcnt(0)" ::: "memory");
    __builtin_amdgcn_sched_barrier(0);

    // ---- matvec + wave reduce (reads own wave's hA/hB region only) ----
    float4 acc[BPG] = {{0,0,0,0},{0,0,0,0},{0,0,0,0},{0,0,0,0}};
    if (s >= 1) {
      if (!isL1) {
        fma_mv_lds(acc, wregB, hA, jg);
      } else {
        fma_mv_lds(acc, wregA, hA, jg);             // W_ih1 * h0_{s-1}
        if (s >= 2) fma_mv_lds(acc, wregB, hB, jg); // + W_hh1 * h1_{s-2}
      }
#pragma unroll
      for (int b = 0; b < BPG; ++b) {
        acc[b].x += __shfl_down(acc[b].x, 32); acc[b].y += __shfl_down(acc[b].y, 32);
        acc[b].z += __shfl_down(acc[b].z, 32); acc[b].w += __shfl_down(acc[b].w, 32);
        acc[b].x += __shfl_down(acc[b].x, 16); acc[b].y += __shfl_down(acc[b].y, 16);
        acc[b].z += __shfl_down(acc[b].z, 16); acc[b].w += __shfl_down(acc[b].w, 16);
      }
      if (wl < 16) {
#pragma unroll
        for (int b = 0; b < BPG; ++b) {
          part[sp][wave][wl][b * 4 + 0] = acc[b].x;
          part[sp][wave][wl][b * 4 + 1] = acc[b].y;
          part[sp][wave][wl][b * 4 + 2] = acc[b].z;
          part[sp][wave][wl][b * 4 + 3] = acc[b].w;
        }
      }
    }
    __syncthreads();   // the single per-step barrier: part[sp] visible

    // ---- finalize (waves 0-3): reduce + tanh + LL-packet publish ----
    if (tid < 256) {
      if (!isL1) {
        float v = xv;
        if (s >= 1) {
#pragma unroll
          for (int w = 0; w < 8; ++w)
            v += part[sp][w][fo >> 2][fbb * 4 + (fo & 3)];
        }
        float h = tanhf(v);
        float* pw = pk + (size_t)(s & (RING - 1)) * SLOTF + wpo;
        float2 pkt; pkt.x = h; pkt.y = __uint_as_float((unsigned)(s + 1));
        asm volatile("global_store_dwordx2 %0, %1, off sc0 sc1"
                     :: "v"(pw), "v"(pkt) : "memory");
      } else if (s >= 1) {
        float v = bs;
#pragma unroll
        for (int w = 0; w < 8; ++w)
          v += part[sp][w][fo >> 2][fbb * 4 + (fo & 3)];
        float h = tanhf(v);
        pacc += h;
        float* pw = pk + (size_t)(RING + ((s - 1) & (RING - 1))) * SLOTF + wpo;
        float2 pkt; pkt.x = h; pkt.y = __uint_as_float((unsigned)s);
        asm volatile("global_store_dwordx2 %0, %1, off sc0 sc1"
                     :: "v"(pw), "v"(pkt) : "memory");
      }
      // no vmcnt wait: the packet store IS the release
    }

    // ---- periodic full barrier (skew bound: drift <= BARK < RING) ----
    if ((s & (BARK - 1)) == (BARK - 1)) {
      unsigned bt = (unsigned)((s >> 5) + 1);
      if (tid == 0) {
        unsigned* fp = flg + role * 32;
        asm volatile("global_store_dword %0, %1, off sc0 sc1"
                     :: "v"(fp), "v"(bt) : "memory");
      }
      if (tid < LBLK) {
        const unsigned* fp = flg + tid * 32;
        unsigned v;
        do {
          asm volatile("global_load_dword %0, %1, off sc0 sc1\n\ts_waitcnt vmcnt(0)"
                       : "=v"(v) : "v"(fp) : "memory");
          if (v < bt) __builtin_amdgcn_s_sleep(2);
        } while (v < bt);
      }
      __syncthreads();
    }
  }

  // ---- L1 epilogue: h1_511 from h0_511 (slot 63, tag 512) and
  //      h1_510 (slot 62, tag 511). part[0] is free after the final sync. ----
  if (isL1) {
    float4 a0, a1, b0, b1;
    const float* pa = pk + (size_t)((SS - 1) & (RING - 1)) * SLOTF + toff;
    const float* pb = pk + (size_t)(RING + ((SS - 2) & (RING - 1))) * SLOTF + toff;
    poll4(pa, (unsigned)SS, pb, (unsigned)(SS - 1), a0, a1, b0, b1);
    scat(hA, q0, a0, a1);
    scat(hB, q0, b0, b1);
    asm volatile("s_waitcnt lgkmcnt(0)" ::: "memory");
    __builtin_amdgcn_sched_barrier(0);
    float4 acc[BPG] = {{0,0,0,0},{0,0,0,0},{0,0,0,0},{0,0,0,0}};
    fma_mv_lds(acc, wregA, hA, jg);
    fma_mv_lds(acc, wregB, hB, jg);
#pragma unroll
    for (int b = 0; b < BPG; ++b) {
      acc[b].x += __shfl_down(acc[b].x, 32); acc[b].y += __shfl_down(acc[b].y, 32);
      acc[b].z += __shfl_down(acc[b].z, 32); acc[b].w += __shfl_down(acc[b].w, 32);
      acc[b].x += __shfl_down(acc[b].x, 16); acc[b].y += __shfl_down(acc[b].y, 16);
      acc[b].z += __shfl_down(acc[b].z, 16); acc[b].w += __shfl_down(acc[b].w, 16);
    }
    if (wl < 16) {
#pragma unroll
      for (int b = 0; b < BPG; ++b) {
        part[0][wave][wl][b * 4 + 0] = acc[b].x;
        part[0][wave][wl][b * 4 + 1] = acc[b].y;
        part[0][wave][wl][b * 4 + 2] = acc[b].z;
        part[0][wave][wl][b * 4 + 3] = acc[b].w;
      }
    }
    __syncthreads();
    if (tid < 256) {
      float v = bs;
#pragma unroll
      for (int w = 0; w < 8; ++w)
        v += part[0][w][fo >> 2][fbb * 4 + (fo & 3)];
      pacc += tanhf(v);
      pooled[(size_t)(grp * BPG + fbb) * HH + fog] = pacc * (1.0f / SS);
    }
  }
}

// Final head: out[b][c] = sum_k pooled[b][k] * W_out[c][k] + b_out[c]
__global__ void out_kernel(const float* __restrict__ pooled,
                           const float* __restrict__ W_out,
                           const float* __restrict__ b_out,
                           float* __restrict__ out) {
  int tid = threadIdx.x;
  if (tid >= BB * 2) return;
  int b = tid >> 1, c = tid & 1;
  float acc = b_out[c];
  for (int k = 0; k < HH; ++k)
    acc += pooled[(size_t)b * HH + k] * W_out[(size_t)c * HH + k];
  out[(size_t)b * 2 + c] = acc;
}

extern "C" void kernel_launch(void* const* d_in, const int* in_sizes, int n_in,
                              void* d_out, int out_size, void* d_ws, size_t ws_size,
                              hipStream_t stream) {
  const int*   x     = (const int*)d_in[0];
  const float* emb   = (const float*)d_in[1];
  const float* W_ih0 = (const float*)d_in[2];
  const float* W_hh0 = (const float*)d_in[3];
  const float* b_ih0 = (const float*)d_in[4];
  const float* b_hh0 = (const float*)d_in[5];
  const float* W_ih1 = (const float*)d_in[6];
  const float* W_hh1 = (const float*)d_in[7];
  const float* b_ih1 = (const float*)d_in[8];
  const float* b_hh1 = (const float*)d_in[9];
  const float* W_out = (const float*)d_in[10];
  const float* b_out = (const float*)d_in[11];

  float* ws = (float*)d_ws;
  const size_t NBSH = (size_t)BB * SS * HH;            // 16777216
  const size_t PKF  = (size_t)NGROUPS * GPKF;          // 8,388,608 floats (32MB)
  float* xp      = ws;                    // 64 MB
  float* WThh0   = ws + NBSH;             // 1 MB
  float* WTih1   = WThh0 + HH * HH;       // 1 MB
  float* WThh1   = WTih1 + HH * HH;       // 1 MB
  float* pooled  = WThh1 + HH * HH;       // 128 KB
  float* pkts    = pooled + BB * HH;      // 32 MB
  unsigned* flags = (unsigned*)(pkts + PKF);  // 32 KB

  init_sync<<<4096, 256, 0, stream>>>(pkts, flags);

  dim3 tb(32, 8), tg(16, 16);
  transpose512<<<tg, tb, 0, stream>>>(W_hh0, WThh0);
  transpose512<<<tg, tb, 0, stream>>>(W_ih1, WTih1);
  transpose512<<<tg, tb, 0, stream>>>(W_hh1, WThh1);

  dim3 gg(512, 8);
  xp_gemm<EE, true><<<gg, 256, 0, stream>>>(nullptr, x, emb, W_ih0, b_ih0, b_hh0, xp);
  rec_fused<<<NGROUPS * LBLK, RECT, 0, stream>>>(
      xp, WThh0, WTih1, WThh1, b_ih1, b_hh1, pooled, pkts, flags);
  out_kernel<<<1, 128, 0, stream>>>(pooled, W_out, b_out, (float*)d_out);
}

// Round 16
// 1676.489 us; speedup vs baseline: 1.3411x; 1.0931x over previous
//
#include <hip/hip_runtime.h>
#include <math.h>

// Problem constants
#define BB 64      // batch
#define SS 512     // seq
#define EE 256     // embed
#define HH 512     // hidden

// Round-16: r15 base + BATCH-PHASE PIPELINING (2 phases x 2 batches).
// The 4 batches in a group are independent chains. Phase A (b0,b1) and
// phase B (b2,b3) alternate within each step with separate packet regions
// and part[] buffers: while A's published h crosses the IC (~0.6us), the
// block computes B -- by A's next poll the packets are visible, taking the
// IC round trip OFF the critical path. Finalize-A = waves 0-1, finalize-B
// = waves 2-3 (each thread's batch == tid>>6, as before), so one phase's
// finalize tail overlaps the other phase's poll/FMA.
// Everything else r15-proven: wave-private poll->scat->FMA (1 dwordx4 per
// lane now: 2 packets), LL {h,tag} packets, s_sleep polls, RING/BARK 64/32.
#define NGROUPS 16
#define GSLICES 8          // slices per layer per group
#define LBLK 16            // blocks per group (2 layers x 8 slices)
#define BPG 4              // batches per group
#define BPP 2              // batches per phase
#define RECT 512           // threads per rec block
#define RING 64            // ring slots per (layer,phase) chain
#define BARK 32            // full barrier every BARK steps

#define SLOTF2 (GSLICES * 256)       // floats per slot: 1024 pkts x 2
#define GPKF   (4 * RING * SLOTF2)   // 4 regions (2 layers x 2 phases)

// ---------------------------------------------------------------------------

// W transpose: WT[j][i] = W[i][j], 512x512
__global__ void transpose512(const float* __restrict__ in, float* __restrict__ out) {
  __shared__ float tile[32][33];
  int bx = blockIdx.x * 32, by = blockIdx.y * 32;
  int x = threadIdx.x, y0 = threadIdx.y;  // block (32,8)
  for (int dy = 0; dy < 32; dy += 8)
    tile[y0 + dy][x] = in[(size_t)(by + y0 + dy) * HH + bx + x];
  __syncthreads();
  for (int dy = 0; dy < 32; dy += 8)
    out[(size_t)(bx + y0 + dy) * HH + by + x] = tile[x][y0 + dy];
}

// Tiled GEMM with gather: C[m][n] = sum_k emb[x[m]][k] * Wn[n][k] + b1[n]+b2[n]
template <int K, bool GATHER>
__global__ __launch_bounds__(256) void xp_gemm(
    const float* __restrict__ Asrc, const int* __restrict__ xidx,
    const float* __restrict__ emb, const float* __restrict__ Wn,
    const float* __restrict__ bias1, const float* __restrict__ bias2,
    float* __restrict__ C) {
  const int tid = threadIdx.x;
  const int m0 = blockIdx.x * 64;
  const int n0 = blockIdx.y * 64;
  __shared__ alignas(16) float As[32][68];
  __shared__ alignas(16) float Bs[32][68];
  __shared__ int xs[64];
  if (GATHER) {
    if (tid < 64) xs[tid] = xidx[m0 + tid];
    __syncthreads();
  }
  float acc[4][4] = {};
  const int ty = tid >> 4, tx = tid & 15;
  const int row = tid >> 2;          // 0..63
  const int kc = (tid & 3) * 8;      // 0,8,16,24

  for (int k0 = 0; k0 < K; k0 += 32) {
    const float* ap;
    if (GATHER) ap = emb + (size_t)xs[row] * EE + (k0 + kc);
    else        ap = Asrc + (size_t)(m0 + row) * K + (k0 + kc);
    float4 av0 = *(const float4*)ap;
    float4 av1 = *(const float4*)(ap + 4);
    const float* bp = Wn + (size_t)(n0 + row) * K + (k0 + kc);
    float4 bv0 = *(const float4*)bp;
    float4 bv1 = *(const float4*)(bp + 4);
    __syncthreads();
    As[kc + 0][row] = av0.x; As[kc + 1][row] = av0.y;
    As[kc + 2][row] = av0.z; As[kc + 3][row] = av0.w;
    As[kc + 4][row] = av1.x; As[kc + 5][row] = av1.y;
    As[kc + 6][row] = av1.z; As[kc + 7][row] = av1.w;
    Bs[kc + 0][row] = bv0.x; Bs[kc + 1][row] = bv0.y;
    Bs[kc + 2][row] = bv0.z; Bs[kc + 3][row] = bv0.w;
    Bs[kc + 4][row] = bv1.x; Bs[kc + 5][row] = bv1.y;
    Bs[kc + 6][row] = bv1.z; Bs[kc + 7][row] = bv1.w;
    __syncthreads();
#pragma unroll 8
    for (int k = 0; k < 32; ++k) {
      float4 av = *(const float4*)&As[k][ty * 4];
      float4 bv = *(const float4*)&Bs[k][tx * 4];
      acc[0][0] += av.x * bv.x; acc[0][1] += av.x * bv.y;
      acc[0][2] += av.x * bv.z; acc[0][3] += av.x * bv.w;
      acc[1][0] += av.y * bv.x; acc[1][1] += av.y * bv.y;
      acc[1][2] += av.y * bv.z; acc[1][3] += av.y * bv.w;
      acc[2][0] += av.z * bv.x; acc[2][1] += av.z * bv.y;
      acc[2][2] += av.z * bv.z; acc[2][3] += av.z * bv.w;
      acc[3][0] += av.w * bv.x; acc[3][1] += av.w * bv.y;
      acc[3][2] += av.w * bv.z; acc[3][3] += av.w * bv.w;
    }
  }
  float bj[4];
#pragma unroll
  for (int j = 0; j < 4; ++j) {
    int n = n0 + tx * 4 + j;
    bj[j] = bias1[n] + bias2[n];
  }
#pragma unroll
  for (int i = 0; i < 4; ++i) {
    float4 cv = make_float4(acc[i][0] + bj[0], acc[i][1] + bj[1],
                            acc[i][2] + bj[2], acc[i][3] + bj[3]);
    *(float4*)&C[(size_t)(m0 + ty * 4 + i) * HH + n0 + tx * 4] = cv;
  }
}

// Zero packet region + barrier flags AT THE IC (grid-stride). Every launch.
__global__ void init_sync(float* __restrict__ pkts, unsigned* __restrict__ flags) {
  const size_t n = (size_t)NGROUPS * GPKF;
  const size_t stride = (size_t)gridDim.x * 256;
  for (size_t i = (size_t)blockIdx.x * 256 + threadIdx.x; i < n; i += stride)
    __hip_atomic_store(&pkts[i], 0.f, __ATOMIC_RELAXED, __HIP_MEMORY_SCOPE_SYSTEM);
  const size_t m = NGROUPS * LBLK * 32;
  for (size_t i = (size_t)blockIdx.x * 256 + threadIdx.x; i < m; i += stride)
    __hip_atomic_store(&flags[i], 0u, __ATOMIC_RELAXED, __HIP_MEMORY_SCOPE_SYSTEM);
}

__device__ __forceinline__ void fma4(float4& d, const float4 w, const float s) {
  d.x = __builtin_fmaf(w.x, s, d.x);
  d.y = __builtin_fmaf(w.y, s, d.y);
  d.z = __builtin_fmaf(w.z, s, d.z);
  d.w = __builtin_fmaf(w.w, s, d.w);
}

// Poll 2 packets (1 dwordx4); s_sleep backoff. Early-clobber (loop reuses p).
__device__ __forceinline__ float4 poll1(const float* p, unsigned tg) {
  float4 u;
  for (;;) {
    asm volatile("global_load_dwordx4 %0, %1, off sc0 sc1\n\ts_waitcnt vmcnt(0)"
                 : "=&v"(u) : "v"(p) : "memory");
    if (__float_as_uint(u.y) == tg && __float_as_uint(u.w) == tg) break;
    __builtin_amdgcn_s_sleep(1);
  }
  return u;
}

// Poll 2+2 packets from two regions in one retry loop.
__device__ __forceinline__ void poll1x2(const float* pa, unsigned tga,
                                        const float* pb, unsigned tgb,
                                        float4& a, float4& b) {
  for (;;) {
    asm volatile("global_load_dwordx4 %0, %2, off sc0 sc1\n\t"
                 "global_load_dwordx4 %1, %3, off sc0 sc1\n\t"
                 "s_waitcnt vmcnt(0)"
                 : "=&v"(a), "=&v"(b) : "v"(pa), "v"(pb) : "memory");
    if (__float_as_uint(a.y) == tga && __float_as_uint(a.w) == tga &&
        __float_as_uint(b.y) == tgb && __float_as_uint(b.w) == tgb) break;
    __builtin_amdgcn_s_sleep(1);
  }
}

// matvec over one phase's 2 batches from LDS h[2][HH]
__device__ __forceinline__ void fma_mv2(float4 acc[2], const float4 wreg[16],
                                        const float* h, int jg) {
#pragma unroll
  for (int q = 0; q < 4; ++q) {
    float4 w0 = wreg[q * 4 + 0], w1 = wreg[q * 4 + 1];
    float4 w2 = wreg[q * 4 + 2], w3 = wreg[q * 4 + 3];
#pragma unroll
    for (int b = 0; b < BPP; ++b) {
      float4 hv = *(const float4*)&h[b * HH + jg * 16 + q * 4];
      fma4(acc[b], w0, hv.x);
      fma4(acc[b], w1, hv.y);
      fma4(acc[b], w2, hv.z);
      fma4(acc[b], w3, hv.w);
    }
  }
}

// Fused 2-layer, 2-phase recurrence. bid: grp = bid&15, role = bid>>4
// (0..7 = L0 slices, 8..15 = L1 slices). Packet regions r = layer*2+phase;
// chain tags as r15 per (layer,phase).
__global__ __launch_bounds__(RECT, 2) void rec_fused(
    const float* __restrict__ xp,      // [BB][SS][HH]
    const float* __restrict__ WThh0,   // [HH][HH]
    const float* __restrict__ WTih1,   // [HH][HH]
    const float* __restrict__ WThh1,   // [HH][HH]
    const float* __restrict__ b_ih1,
    const float* __restrict__ b_hh1,
    float* __restrict__ pooled,        // [BB][HH]
    float* __restrict__ pkts,          // [NGROUPS][4][RING][SLOTF2]
    unsigned* __restrict__ flags) {    // [NGROUPS][LBLK][32]
  const int tid = threadIdx.x;
  const int bid = blockIdx.x;
  const int grp = bid & 15;
  const int role = bid >> 4;          // 0..15
  const bool isL1 = role >= GSLICES;
  const int slice = role & 7;
  const int oo4 = tid & 15;
  const int jg = tid >> 4;            // 0..31
  const int obase = slice * 64 + oo4 * 4;

  // ---- weights into registers (once); pin against remat (round-4 lesson) --
  float4 wregA[16], wregB[16];
  {
    const float* wb = isL1 ? WThh1 : WThh0;
#pragma unroll
    for (int j = 0; j < 16; ++j)
      wregB[j] = *(const float4*)&wb[(size_t)(jg * 16 + j) * HH + obase];
#pragma unroll
    for (int j = 0; j < 16; ++j)
      asm volatile("" : "+v"(wregB[j].x), "+v"(wregB[j].y),
                        "+v"(wregB[j].z), "+v"(wregB[j].w));
  }
  if (isL1) {
#pragma unroll
    for (int j = 0; j < 16; ++j)
      wregA[j] = *(const float4*)&WTih1[(size_t)(jg * 16 + j) * HH + obase];
#pragma unroll
    for (int j = 0; j < 16; ++j)
      asm volatile("" : "+v"(wregA[j].x), "+v"(wregA[j].y),
                        "+v"(wregA[j].z), "+v"(wregA[j].w));
  }

  float* pk = pkts + (size_t)grp * GPKF;
  unsigned* flg = flags + grp * (LBLK * 32);

  __shared__ alignas(16) float hs0A[BPP * HH];   // 4 KB each
  __shared__ alignas(16) float hs0B[BPP * HH];
  __shared__ alignas(16) float hs1A[BPP * HH];   // L1 only
  __shared__ alignas(16) float hs1B[BPP * HH];
  __shared__ float part[2][8][16][9];            // [phase][wave][oo4][b*4+c]

  const int wave = tid >> 6, wl = tid & 63;
  const int fo = tid & 63;
  const int fbb = (tid >> 6) & 3;          // batch (tid<256); wave == batch
  const int fbl = (tid >> 6) & 1;          // batch within phase
  const int fog = slice * 64 + fo;
  const size_t fxbase = (size_t)(grp * BPG + fbb) * (SS * HH) + fog;
  float pacc = 0.f;
  float bs = 0.f;
  if (tid < 256) bs = b_ih1[fog] + b_hh1[fog];

  const int toff = wave * 256 + wl * 4;           // consumer dwordx4 float off
  const int wpo = slice * 256 + fo * 4 + fbl * 2; // producer pkt float off

  for (int s = 0; s < SS; ++s) {
    float xv = 0.f;
    if (!isL1 && tid < 256) xv = xp[fxbase + (size_t)s * HH];

    // =============== PHASE A (batches 0,1) ===============
    if (s >= 1) {
      const float* p0 = pk + (size_t)((0 * RING) + ((s - 1) & (RING - 1))) * SLOTF2 + toff;
      if (!isL1) {
        float4 u = poll1(p0, (unsigned)s);
        hs0A[tid] = u.x; hs0A[HH + tid] = u.z;
      } else if (s >= 2) {
        const float* p1 = pk + (size_t)((2 * RING) + ((s - 2) & (RING - 1))) * SLOTF2 + toff;
        float4 a, b;
        poll1x2(p0, (unsigned)s, p1, (unsigned)(s - 1), a, b);
        hs0A[tid] = a.x; hs0A[HH + tid] = a.z;
        hs1A[tid] = b.x; hs1A[HH + tid] = b.z;
      } else {
        float4 a = poll1(p0, 1u);
        hs0A[tid] = a.x; hs0A[HH + tid] = a.z;
      }
    }
    asm volatile("s_waitcnt lgkmcnt(0)" ::: "memory");
    __builtin_amdgcn_sched_barrier(0);
    {
      float4 acc[BPP] = {{0,0,0,0},{0,0,0,0}};
      if (s >= 1) {
        if (!isL1) fma_mv2(acc, wregB, hs0A, jg);
        else {
          fma_mv2(acc, wregA, hs0A, jg);
          if (s >= 2) fma_mv2(acc, wregB, hs1A, jg);
        }
#pragma unroll
        for (int b = 0; b < BPP; ++b) {
          acc[b].x += __shfl_down(acc[b].x, 32); acc[b].y += __shfl_down(acc[b].y, 32);
          acc[b].z += __shfl_down(acc[b].z, 32); acc[b].w += __shfl_down(acc[b].w, 32);
          acc[b].x += __shfl_down(acc[b].x, 16); acc[b].y += __shfl_down(acc[b].y, 16);
          acc[b].z += __shfl_down(acc[b].z, 16); acc[b].w += __shfl_down(acc[b].w, 16);
        }
        if (wl < 16) {
#pragma unroll
          for (int b = 0; b < BPP; ++b) {
            part[0][wave][wl][b * 4 + 0] = acc[b].x;
            part[0][wave][wl][b * 4 + 1] = acc[b].y;
            part[0][wave][wl][b * 4 + 2] = acc[b].z;
            part[0][wave][wl][b * 4 + 3] = acc[b].w;
          }
        }
      }
    }
    __syncthreads();   // sync-A
    if (tid < 128) {   // finalize A (waves 0-1 = batches 0,1)
      if (!isL1) {
        float v = xv;
        if (s >= 1) {
#pragma unroll
          for (int w = 0; w < 8; ++w) v += part[0][w][fo >> 2][fbl * 4 + (fo & 3)];
        }
        float h = tanhf(v);
        float* pw = pk + (size_t)((0 * RING) + (s & (RING - 1))) * SLOTF2 + wpo;
        float2 pp; pp.x = h; pp.y = __uint_as_float((unsigned)(s + 1));
        asm volatile("global_store_dwordx2 %0, %1, off sc0 sc1"
                     :: "v"(pw), "v"(pp) : "memory");
      } else if (s >= 1) {
        float v = bs;
#pragma unroll
        for (int w = 0; w < 8; ++w) v += part[0][w][fo >> 2][fbl * 4 + (fo & 3)];
        float h = tanhf(v);
        pacc += h;
        float* pw = pk + (size_t)((2 * RING) + ((s - 1) & (RING - 1))) * SLOTF2 + wpo;
        float2 pp; pp.x = h; pp.y = __uint_as_float((unsigned)s);
        asm volatile("global_store_dwordx2 %0, %1, off sc0 sc1"
                     :: "v"(pw), "v"(pp) : "memory");
      }
    }

    // =============== PHASE B (batches 2,3) ===============
    if (s >= 1) {
      const float* p0 = pk + (size_t)((1 * RING) + ((s - 1) & (RING - 1))) * SLOTF2 + toff;
      if (!isL1) {
        float4 u = poll1(p0, (unsigned)s);
        hs0B[tid] = u.x; hs0B[HH + tid] = u.z;
      } else if (s >= 2) {
        const float* p1 = pk + (size_t)((3 * RING) + ((s - 2) & (RING - 1))) * SLOTF2 + toff;
        float4 a, b;
        poll1x2(p0, (unsigned)s, p1, (unsigned)(s - 1), a, b);
        hs0B[tid] = a.x; hs0B[HH + tid] = a.z;
        hs1B[tid] = b.x; hs1B[HH + tid] = b.z;
      } else {
        float4 a = poll1(p0, 1u);
        hs0B[tid] = a.x; hs0B[HH + tid] = a.z;
      }
    }
    asm volatile("s_waitcnt lgkmcnt(0)" ::: "memory");
    __builtin_amdgcn_sched_barrier(0);
    {
      float4 acc[BPP] = {{0,0,0,0},{0,0,0,0}};
      if (s >= 1) {
        if (!isL1) fma_mv2(acc, wregB, hs0B, jg);
        else {
          fma_mv2(acc, wregA, hs0B, jg);
          if (s >= 2) fma_mv2(acc, wregB, hs1B, jg);
        }
#pragma unroll
        for (int b = 0; b < BPP; ++b) {
          acc[b].x += __shfl_down(acc[b].x, 32); acc[b].y += __shfl_down(acc[b].y, 32);
          acc[b].z += __shfl_down(acc[b].z, 32); acc[b].w += __shfl_down(acc[b].w, 32);
          acc[b].x += __shfl_down(acc[b].x, 16); acc[b].y += __shfl_down(acc[b].y, 16);
          acc[b].z += __shfl_down(acc[b].z, 16); acc[b].w += __shfl_down(acc[b].w, 16);
        }
        if (wl < 16) {
#pragma unroll
          for (int b = 0; b < BPP; ++b) {
            part[1][wave][wl][b * 4 + 0] = acc[b].x;
            part[1][wave][wl][b * 4 + 1] = acc[b].y;
            part[1][wave][wl][b * 4 + 2] = acc[b].z;
            part[1][wave][wl][b * 4 + 3] = acc[b].w;
          }
        }
      }
    }
    __syncthreads();   // sync-B
    if (tid >= 128 && tid < 256) {   // finalize B (waves 2-3 = batches 2,3)
      if (!isL1) {
        float v = xv;
        if (s >= 1) {
#pragma unroll
          for (int w = 0; w < 8; ++w) v += part[1][w][fo >> 2][fbl * 4 + (fo & 3)];
        }
        float h = tanhf(v);
        float* pw = pk + (size_t)((1 * RING) + (s & (RING - 1))) * SLOTF2 + wpo;
        float2 pp; pp.x = h; pp.y = __uint_as_float((unsigned)(s + 1));
        asm volatile("global_store_dwordx2 %0, %1, off sc0 sc1"
                     :: "v"(pw), "v"(pp) : "memory");
      } else if (s >= 1) {
        float v = bs;
#pragma unroll
        for (int w = 0; w < 8; ++w) v += part[1][w][fo >> 2][fbl * 4 + (fo & 3)];
        float h = tanhf(v);
        pacc += h;
        float* pw = pk + (size_t)((3 * RING) + ((s - 1) & (RING - 1))) * SLOTF2 + wpo;
        float2 pp; pp.x = h; pp.y = __uint_as_float((unsigned)s);
        asm volatile("global_store_dwordx2 %0, %1, off sc0 sc1"
                     :: "v"(pw), "v"(pp) : "memory");
      }
    }

    // ---- periodic full barrier (skew bound: drift <= BARK < RING) ----
    if ((s & (BARK - 1)) == (BARK - 1)) {
      unsigned bt = (unsigned)((s >> 5) + 1);
      if (tid == 0) {
        unsigned* fp = flg + role * 32;
        asm volatile("global_store_dword %0, %1, off sc0 sc1"
                     :: "v"(fp), "v"(bt) : "memory");
      }
      if (tid < LBLK) {
        const unsigned* fp = flg + tid * 32;
        unsigned v;
        do {
          asm volatile("global_load_dword %0, %1, off sc0 sc1\n\ts_waitcnt vmcnt(0)"
                       : "=v"(v) : "v"(fp) : "memory");
          if (v < bt) __builtin_amdgcn_s_sleep(2);
        } while (v < bt);
      }
      __syncthreads();
    }
  }

  // ---- L1 epilogue: h1_511 per phase (h0_511 tag 512, h1_510 tag 511) ----
  if (isL1) {
    {
      const float* p0 = pk + (size_t)((0 * RING) + ((SS - 1) & (RING - 1))) * SLOTF2 + toff;
      const float* p1 = pk + (size_t)((2 * RING) + ((SS - 2) & (RING - 1))) * SLOTF2 + toff;
      float4 a, b;
      poll1x2(p0, (unsigned)SS, p1, (unsigned)(SS - 1), a, b);
      hs0A[tid] = a.x; hs0A[HH + tid] = a.z;
      hs1A[tid] = b.x; hs1A[HH + tid] = b.z;
      const float* q0 = pk + (size_t)((1 * RING) + ((SS - 1) & (RING - 1))) * SLOTF2 + toff;
      const float* q1 = pk + (size_t)((3 * RING) + ((SS - 2) & (RING - 1))) * SLOTF2 + toff;
      float4 c, d;
      poll1x2(q0, (unsigned)SS, q1, (unsigned)(SS - 1), c, d);
      hs0B[tid] = c.x; hs0B[HH + tid] = c.z;
      hs1B[tid] = d.x; hs1B[HH + tid] = d.z;
    }
    asm volatile("s_waitcnt lgkmcnt(0)" ::: "memory");
    __builtin_amdgcn_sched_barrier(0);
    for (int ph = 0; ph < 2; ++ph) {
      float4 acc[BPP] = {{0,0,0,0},{0,0,0,0}};
      const float* h0 = ph ? hs0B : hs0A;
      const float* h1 = ph ? hs1B : hs1A;
      fma_mv2(acc, wregA, h0, jg);
      fma_mv2(acc, wregB, h1, jg);
#pragma unroll
      for (int b = 0; b < BPP; ++b) {
        acc[b].x += __shfl_down(acc[b].x, 32); acc[b].y += __shfl_down(acc[b].y, 32);
        acc[b].z += __shfl_down(acc[b].z, 32); acc[b].w += __shfl_down(acc[b].w, 32);
        acc[b].x += __shfl_down(acc[b].x, 16); acc[b].y += __shfl_down(acc[b].y, 16);
        acc[b].z += __shfl_down(acc[b].z, 16); acc[b].w += __shfl_down(acc[b].w, 16);
      }
      if (wl < 16) {
#pragma unroll
        for (int b = 0; b < BPP; ++b) {
          part[ph][wave][wl][b * 4 + 0] = acc[b].x;
          part[ph][wave][wl][b * 4 + 1] = acc[b].y;
          part[ph][wave][wl][b * 4 + 2] = acc[b].z;
          part[ph][wave][wl][b * 4 + 3] = acc[b].w;
        }
      }
    }
    __syncthreads();
    if (tid < 256) {
      int ph = tid >> 7;
      float v = bs;
#pragma unroll
      for (int w = 0; w < 8; ++w) v += part[ph][w][fo >> 2][fbl * 4 + (fo & 3)];
      pacc += tanhf(v);
      pooled[(size_t)(grp * BPG + fbb) * HH + fog] = pacc * (1.0f / SS);
    }
  }
}

// Final head: out[b][c] = sum_k pooled[b][k] * W_out[c][k] + b_out[c]
__global__ void out_kernel(const float* __restrict__ pooled,
                           const float* __restrict__ W_out,
                           const float* __restrict__ b_out,
                           float* __restrict__ out) {
  int tid = threadIdx.x;
  if (tid >= BB * 2) return;
  int b = tid >> 1, c = tid & 1;
  float acc = b_out[c];
  for (int k = 0; k < HH; ++k)
    acc += pooled[(size_t)b * HH + k] * W_out[(size_t)c * HH + k];
  out[(size_t)b * 2 + c] = acc;
}

extern "C" void kernel_launch(void* const* d_in, const int* in_sizes, int n_in,
                              void* d_out, int out_size, void* d_ws, size_t ws_size,
                              hipStream_t stream) {
  const int*   x     = (const int*)d_in[0];
  const float* emb   = (const float*)d_in[1];
  const float* W_ih0 = (const float*)d_in[2];
  const float* W_hh0 = (const float*)d_in[3];
  const float* b_ih0 = (const float*)d_in[4];
  const float* b_hh0 = (const float*)d_in[5];
  const float* W_ih1 = (const float*)d_in[6];
  const float* W_hh1 = (const float*)d_in[7];
  const float* b_ih1 = (const float*)d_in[8];
  const float* b_hh1 = (const float*)d_in[9];
  const float* W_out = (const float*)d_in[10];
  const float* b_out = (const float*)d_in[11];

  float* ws = (float*)d_ws;
  const size_t NBSH = (size_t)BB * SS * HH;            // 16777216
  const size_t PKF  = (size_t)NGROUPS * GPKF;          // 8,388,608 floats (32MB)
  float* xp      = ws;                    // 64 MB
  float* WThh0   = ws + NBSH;             // 1 MB
  float* WTih1   = WThh0 + HH * HH;       // 1 MB
  float* WThh1   = WTih1 + HH * HH;       // 1 MB
  float* pooled  = WThh1 + HH * HH;       // 128 KB
  float* pkts    = pooled + BB * HH;      // 32 MB
  unsigned* flags = (unsigned*)(pkts + PKF);  // 32 KB

  init_sync<<<4096, 256, 0, stream>>>(pkts, flags);

  dim3 tb(32, 8), tg(16, 16);
  transpose512<<<tg, tb, 0, stream>>>(W_hh0, WThh0);
  transpose512<<<tg, tb, 0, stream>>>(W_ih1, WTih1);
  transpose512<<<tg, tb, 0, stream>>>(W_hh1, WThh1);

  dim3 gg(512, 8);
  xp_gemm<EE, true><<<gg, 256, 0, stream>>>(nullptr, x, emb, W_ih0, b_ih0, b_hh0, xp);
  rec_fused<<<NGROUPS * LBLK, RECT, 0, stream>>>(
      xp, WThh0, WTih1, WThh1, b_ih1, b_hh1, pooled, pkts, flags);
  out_kernel<<<1, 128, 0, stream>>>(pooled, W_out, b_out, (float*)d_out);
}